// Round 1
// baseline (2539.766 us; speedup 1.0000x reference)
//
#include <hip/hip_runtime.h>

#define NNODES 102400
#define NBATCH 256
#define LSEQ   400
#define SPAD   416   // 8 zero pad rows each side of the 400 valid positions
#define HS     256
#define KDIM   640
#define OC     128
#define NTAP   15
#define H1     512

// ---------------- combine the three conv kernels into one 15-tap weight ----
// Wc[d][ic][oc] = (k15[oc,ic,d] + k11[oc,ic,d-2] + k7[oc,ic,d-4]) / 3
__global__ __launch_bounds__(256) void combine_w(
    const float* __restrict__ k7, const float* __restrict__ k11,
    const float* __restrict__ k15, const float* __restrict__ cb7,
    const float* __restrict__ cb11, const float* __restrict__ cb15,
    float* __restrict__ Wc, float* __restrict__ bc)
{
    int idx = blockIdx.x * 256 + threadIdx.x;
    if (idx < NTAP * HS * OC) {
        int oc = idx & (OC - 1);
        int ic = (idx >> 7) & (HS - 1);
        int dd = idx / (OC * HS);
        float w = k15[(oc * HS + ic) * 15 + dd];
        int t11 = dd - 2;
        if (t11 >= 0 && t11 < 11) w += k11[(oc * HS + ic) * 11 + t11];
        int t7 = dd - 4;
        if (t7 >= 0 && t7 < 7)   w += k7[(oc * HS + ic) * 7 + t7];
        Wc[idx] = w * (1.0f / 3.0f);
    }
    if (idx < OC) bc[idx] = (cb7[idx] + cb11[idx] + cb15[idx]) * (1.0f / 3.0f);
}

// ---------------- emb @ W_le + relu + (x_r + .)/2 scatter into seq ---------
// 64x64 tile, BK=16, 256 threads, 4x4 microtile.
__global__ __launch_bounds__(256) void gemm_emb(
    const float* __restrict__ emb, const int* __restrict__ x_tokens,
    const int* __restrict__ batch_ids, const int* __restrict__ pos_ids,
    const float* __restrict__ emb_table,
    const float* __restrict__ W_le, const float* __restrict__ b_le,
    float* __restrict__ seq)
{
    __shared__ float As[16][68];
    __shared__ float Bs[16][68];
    int tid = threadIdx.x;
    int tx = tid & 15, ty = tid >> 4;
    int row0 = blockIdx.y * 64;
    int c0   = blockIdx.x * 64;

    int lm  = tid >> 2;          // A-load row 0..63
    int lk4 = (tid & 3) * 4;     // A-load k offset
    int bk  = tid >> 4;          // B-load k row 0..15
    int bc4 = (tid & 15) * 4;    // B-load col

    float acc[4][4] = {};
    for (int k0 = 0; k0 < KDIM; k0 += 16) {
        float4 a4 = *(const float4*)&emb[(size_t)(row0 + lm) * KDIM + k0 + lk4];
        As[lk4 + 0][lm] = a4.x; As[lk4 + 1][lm] = a4.y;
        As[lk4 + 2][lm] = a4.z; As[lk4 + 3][lm] = a4.w;
        *(float4*)&Bs[bk][bc4] =
            *(const float4*)&W_le[(size_t)(k0 + bk) * HS + c0 + bc4];
        __syncthreads();
        #pragma unroll
        for (int kk = 0; kk < 16; kk++) {
            float4 av = *(const float4*)&As[kk][ty * 4];
            float4 bv = *(const float4*)&Bs[kk][tx * 4];
            float a[4] = {av.x, av.y, av.z, av.w};
            float bb[4] = {bv.x, bv.y, bv.z, bv.w};
            #pragma unroll
            for (int i = 0; i < 4; i++)
                #pragma unroll
                for (int j = 0; j < 4; j++)
                    acc[i][j] += a[i] * bb[j];
        }
        __syncthreads();
    }
    int cc = c0 + tx * 4;
    float4 blv = *(const float4*)&b_le[cc];
    float bl[4] = {blv.x, blv.y, blv.z, blv.w};
    #pragma unroll
    for (int i = 0; i < 4; i++) {
        int row = row0 + ty * 4 + i;
        int tok = x_tokens[row];
        int b = batch_ids[row], p = pos_ids[row];
        const float* et = &emb_table[tok * HS + cc];
        float4 o;
        float v0 = acc[i][0] + bl[0]; v0 = v0 > 0.f ? v0 : 0.f; o.x = 0.5f * (v0 + et[0]);
        float v1 = acc[i][1] + bl[1]; v1 = v1 > 0.f ? v1 : 0.f; o.y = 0.5f * (v1 + et[1]);
        float v2 = acc[i][2] + bl[2]; v2 = v2 > 0.f ? v2 : 0.f; o.z = 0.5f * (v2 + et[2]);
        float v3 = acc[i][3] + bl[3]; v3 = v3 > 0.f ? v3 : 0.f; o.w = 0.5f * (v3 + et[3]);
        *(float4*)&seq[((size_t)b * SPAD + (p + 8)) * HS + cc] = o;
    }
}

// ---------------- fused 15-tap conv: [B,SPAD,256] -> [B,400,128] -----------
// block = (s-tile of 32) x (all 128 oc), 256 threads, 4s x 4oc microtile
__global__ __launch_bounds__(256) void conv_fused(
    const float* __restrict__ seq, const float* __restrict__ Wc,
    const float* __restrict__ bc, float* __restrict__ convout)
{
    __shared__ float Sin[46][HS];   // rows s0-7 .. s0+38 (seq rows s0+1..s0+46)
    __shared__ float Ws[16][OC];
    int b  = blockIdx.y;
    int s0 = blockIdx.x * 32;
    int tid = threadIdx.x;

    #pragma unroll
    for (int pass = 0; pass < 12; pass++) {
        int idx = pass * 256 + tid;
        int r = idx >> 6;
        int c4 = (idx & 63) * 4;
        if (r < 46) {
            int srow = s0 + 1 + r;
            float4 v = make_float4(0.f, 0.f, 0.f, 0.f);
            if (srow < SPAD)
                v = *(const float4*)&seq[((size_t)b * SPAD + srow) * HS + c4];
            *(float4*)&Sin[r][c4] = v;
        }
    }

    float acc[4][4] = {};
    int oc4 = (tid & 31) * 4;
    int s4  = (tid >> 5) * 4;

    for (int d = 0; d < NTAP; d++) {
        for (int ic0 = 0; ic0 < HS; ic0 += 16) {
            __syncthreads();
            #pragma unroll
            for (int p = 0; p < 2; p++) {
                int q = p * 256 + tid;
                int icr = q >> 5;
                int o4 = (q & 31) * 4;
                *(float4*)&Ws[icr][o4] =
                    *(const float4*)&Wc[((size_t)d * HS + (ic0 + icr)) * OC + o4];
            }
            __syncthreads();
            #pragma unroll
            for (int kk4 = 0; kk4 < 4; kk4++) {
                float av[4][4];
                #pragma unroll
                for (int i = 0; i < 4; i++) {
                    float4 t = *(const float4*)&Sin[s4 + i + d][ic0 + kk4 * 4];
                    av[i][0] = t.x; av[i][1] = t.y; av[i][2] = t.z; av[i][3] = t.w;
                }
                #pragma unroll
                for (int u = 0; u < 4; u++) {
                    float4 wv = *(const float4*)&Ws[kk4 * 4 + u][oc4];
                    #pragma unroll
                    for (int i = 0; i < 4; i++) {
                        acc[i][0] += av[i][u] * wv.x;
                        acc[i][1] += av[i][u] * wv.y;
                        acc[i][2] += av[i][u] * wv.z;
                        acc[i][3] += av[i][u] * wv.w;
                    }
                }
            }
        }
    }

    float4 bv = *(const float4*)&bc[oc4];
    #pragma unroll
    for (int i = 0; i < 4; i++) {
        int s = s0 + s4 + i;
        if (s < LSEQ) {
            float4 o;
            o.x = acc[i][0] + bv.x; o.y = acc[i][1] + bv.y;
            o.z = acc[i][2] + bv.z; o.w = acc[i][3] + bv.w;
            *(float4*)&convout[((size_t)b * LSEQ + s) * OC + oc4] = o;
        }
    }
}

// ---------------- relu(conv @ Wl1 + bl1), summed over s<400 per batch ------
// 64(s) x 64(j) tile, K=128, per-block column-sum then atomicAdd into A_acc
__global__ __launch_bounds__(256) void mlp1_reduce(
    const float* __restrict__ convout, const float* __restrict__ Wl1,
    const float* __restrict__ bl1, float* __restrict__ A_acc)
{
    __shared__ float As[16][68];
    __shared__ float Bs[16][68];
    __shared__ float red[16][64];
    int b  = blockIdx.z;
    int s0 = blockIdx.y * 64;
    int j0 = blockIdx.x * 64;
    int tid = threadIdx.x;
    int tx = tid & 15, ty = tid >> 4;

    int lm  = tid >> 2;
    int lk4 = (tid & 3) * 4;
    int bk  = tid >> 4;
    int bc4 = (tid & 15) * 4;

    float acc[4][4] = {};
    for (int k0 = 0; k0 < OC; k0 += 16) {
        int srow = s0 + lm;
        float4 a4 = make_float4(0.f, 0.f, 0.f, 0.f);
        if (srow < LSEQ)
            a4 = *(const float4*)&convout[((size_t)b * LSEQ + srow) * OC + k0 + lk4];
        As[lk4 + 0][lm] = a4.x; As[lk4 + 1][lm] = a4.y;
        As[lk4 + 2][lm] = a4.z; As[lk4 + 3][lm] = a4.w;
        *(float4*)&Bs[bk][bc4] =
            *(const float4*)&Wl1[(size_t)(k0 + bk) * H1 + j0 + bc4];
        __syncthreads();
        #pragma unroll
        for (int kk = 0; kk < 16; kk++) {
            float4 av = *(const float4*)&As[kk][ty * 4];
            float4 bv = *(const float4*)&Bs[kk][tx * 4];
            float a[4] = {av.x, av.y, av.z, av.w};
            float bb[4] = {bv.x, bv.y, bv.z, bv.w};
            #pragma unroll
            for (int i = 0; i < 4; i++)
                #pragma unroll
                for (int j = 0; j < 4; j++)
                    acc[i][j] += a[i] * bb[j];
        }
        __syncthreads();
    }

    float4 blv = *(const float4*)&bl1[j0 + tx * 4];
    float bl[4] = {blv.x, blv.y, blv.z, blv.w};
    float r[4] = {0.f, 0.f, 0.f, 0.f};
    #pragma unroll
    for (int i = 0; i < 4; i++) {
        int s = s0 + ty * 4 + i;
        if (s < LSEQ) {
            #pragma unroll
            for (int j = 0; j < 4; j++) {
                float v = acc[i][j] + bl[j];
                r[j] += v > 0.f ? v : 0.f;
            }
        }
    }
    #pragma unroll
    for (int j = 0; j < 4; j++) red[ty][tx * 4 + j] = r[j];
    __syncthreads();
    if (tid < 64) {
        float v = 0.f;
        #pragma unroll
        for (int t = 0; t < 16; t++) v += red[t][tid];
        atomicAdd(&A_acc[(size_t)b * H1 + j0 + tid], v);
    }
}

// ---------------- final: out = A_acc @ Wl2 / 512 + bl2 * (400/512) ---------
__global__ __launch_bounds__(256) void final_out(
    const float* __restrict__ A_acc, const float* __restrict__ Wl2,
    const float* __restrict__ bl2, float* __restrict__ out)
{
    __shared__ float a[H1];
    int b = blockIdx.x, tid = threadIdx.x;
    a[tid] = A_acc[(size_t)b * H1 + tid];
    a[tid + 256] = A_acc[(size_t)b * H1 + tid + 256];
    __syncthreads();
    float acc = 0.f;
    for (int k = 0; k < H1; k++)
        acc += a[k] * Wl2[(size_t)k * HS + tid];
    out[(size_t)b * HS + tid] = acc * (1.0f / 512.0f) + bl2[tid] * (400.0f / 512.0f);
}

extern "C" void kernel_launch(void* const* d_in, const int* in_sizes, int n_in,
                              void* d_out, int out_size, void* d_ws, size_t ws_size,
                              hipStream_t stream)
{
    const float* emb       = (const float*)d_in[0];
    const int*   x_tokens  = (const int*)d_in[1];
    // d_in[2] edge_src, d_in[3] edge_dst: DEAD (GAT output unused)
    const int*   batch_ids = (const int*)d_in[4];
    const int*   pos_ids   = (const int*)d_in[5];
    // d_in[6] mask: encoded analytically (s < 400, mean over 512)
    const float* emb_table = (const float*)d_in[7];
    // d_in[8..21]: W_e2g/b_e2g + all GAT params: DEAD
    const float* W_le = (const float*)d_in[22];
    const float* b_le = (const float*)d_in[23];
    const float* k7   = (const float*)d_in[24];
    const float* cb7  = (const float*)d_in[25];
    const float* k11  = (const float*)d_in[26];
    const float* cb11 = (const float*)d_in[27];
    const float* k15  = (const float*)d_in[28];
    const float* cb15 = (const float*)d_in[29];
    const float* Wl1  = (const float*)d_in[30];
    const float* bl1  = (const float*)d_in[31];
    const float* Wl2  = (const float*)d_in[32];
    const float* bl2  = (const float*)d_in[33];
    float* out = (float*)d_out;

    float* seq     = (float*)d_ws;                          // [256][416][256]
    float* convout = seq + (size_t)NBATCH * SPAD * HS;      // [256][400][128]
    float* Wc      = convout + (size_t)NBATCH * LSEQ * OC;  // [15][256][128]
    float* bc      = Wc + (size_t)NTAP * HS * OC;           // [128]
    float* A_acc   = bc + OC;                               // [256][512]

    hipMemsetAsync(seq, 0, (size_t)NBATCH * SPAD * HS * sizeof(float), stream);
    hipMemsetAsync(A_acc, 0, (size_t)NBATCH * H1 * sizeof(float), stream);

    combine_w<<<dim3((NTAP * HS * OC + 255) / 256), 256, 0, stream>>>(
        k7, k11, k15, cb7, cb11, cb15, Wc, bc);
    gemm_emb<<<dim3(4, NNODES / 64), 256, 0, stream>>>(
        emb, x_tokens, batch_ids, pos_ids, emb_table, W_le, b_le, seq);
    conv_fused<<<dim3(13, NBATCH), 256, 0, stream>>>(seq, Wc, bc, convout);
    mlp1_reduce<<<dim3(8, 7, NBATCH), 256, 0, stream>>>(convout, Wl1, bl1, A_acc);
    final_out<<<NBATCH, 256, 0, stream>>>(A_acc, Wl2, bl2, out);
}

// Round 2
// 1200.189 us; speedup vs baseline: 2.1161x; 2.1161x over previous
//
#include <hip/hip_runtime.h>

#define NNODES 102400
#define NBATCH 256
#define LSEQ   400
#define SPAD   416   // 8 zero pad rows each side of the 400 valid positions
#define HS     256
#define KDIM   640
#define OC     128
#define NTAP   15
#define H1     512

typedef __attribute__((ext_vector_type(8))) short short8;
typedef __attribute__((ext_vector_type(4))) float floatx4;

__device__ inline unsigned short f2bf(float f) {
    unsigned u = __builtin_bit_cast(unsigned, f);
    unsigned r = (u + 0x7FFFu + ((u >> 16) & 1u)) >> 16;
    return (unsigned short)r;
}

__device__ inline void gld_lds16(const void* g, void* l) {
    __builtin_amdgcn_global_load_lds(
        (const __attribute__((address_space(1))) unsigned int*)g,
        (__attribute__((address_space(3))) unsigned int*)l, 16, 0, 0);
}

// ------- combine k7/k11/k15 (+/3) into one 15-tap weight, packed in MFMA
// ------- B-fragment order, bf16.  Stage (d,kc): BK=64 ic, all 128 oc.
// ------- elem (d, ic, oc) -> [((d*4+kc)*2+ks)*8+nt][lane=q*16+n][j]
__global__ __launch_bounds__(256) void combine_pack(
    const float* __restrict__ k7, const float* __restrict__ k11,
    const float* __restrict__ k15, const float* __restrict__ cb7,
    const float* __restrict__ cb11, const float* __restrict__ cb15,
    unsigned short* __restrict__ Wpk, float* __restrict__ bc)
{
    int idx = blockIdx.x * 256 + threadIdx.x;
    if (idx < NTAP * HS * OC) {
        int oc = idx & (OC - 1);
        int ic = (idx >> 7) & (HS - 1);
        int d  = idx / (OC * HS);
        float w = k15[(oc * HS + ic) * 15 + d];
        int t11 = d - 2;
        if (t11 >= 0 && t11 < 11) w += k11[(oc * HS + ic) * 11 + t11];
        int t7 = d - 4;
        if (t7 >= 0 && t7 < 7)   w += k7[(oc * HS + ic) * 7 + t7];
        w *= (1.0f / 3.0f);
        int kc = ic >> 6, ks = (ic >> 5) & 1, q = (ic >> 3) & 3, j = ic & 7;
        int nt = oc >> 4, n = oc & 15;
        int pidx = ((((d * 4 + kc) * 2 + ks) * 8 + nt) * 64 + (q * 16 + n)) * 8 + j;
        Wpk[pidx] = f2bf(w);
    }
    if (idx < OC) bc[idx] = (cb7[idx] + cb11[idx] + cb15[idx]) * (1.0f / 3.0f);
}

// ------- emb @ W_le + relu + (x_r + .)/2 scatter into bf16 seq -------------
__global__ __launch_bounds__(256) void gemm_emb(
    const float* __restrict__ emb, const int* __restrict__ x_tokens,
    const int* __restrict__ batch_ids, const int* __restrict__ pos_ids,
    const float* __restrict__ emb_table,
    const float* __restrict__ W_le, const float* __restrict__ b_le,
    unsigned short* __restrict__ seq)
{
    __shared__ float As[16][68];
    __shared__ float Bs[16][68];
    int tid = threadIdx.x;
    int tx = tid & 15, ty = tid >> 4;
    int row0 = blockIdx.y * 64;
    int c0   = blockIdx.x * 64;

    int lm  = tid >> 2;
    int lk4 = (tid & 3) * 4;
    int bk  = tid >> 4;
    int bc4 = (tid & 15) * 4;

    float acc[4][4] = {};
    for (int k0 = 0; k0 < KDIM; k0 += 16) {
        float4 a4 = *(const float4*)&emb[(size_t)(row0 + lm) * KDIM + k0 + lk4];
        As[lk4 + 0][lm] = a4.x; As[lk4 + 1][lm] = a4.y;
        As[lk4 + 2][lm] = a4.z; As[lk4 + 3][lm] = a4.w;
        *(float4*)&Bs[bk][bc4] =
            *(const float4*)&W_le[(size_t)(k0 + bk) * HS + c0 + bc4];
        __syncthreads();
        #pragma unroll
        for (int kk = 0; kk < 16; kk++) {
            float4 av = *(const float4*)&As[kk][ty * 4];
            float4 bv = *(const float4*)&Bs[kk][tx * 4];
            float a[4] = {av.x, av.y, av.z, av.w};
            float bb[4] = {bv.x, bv.y, bv.z, bv.w};
            #pragma unroll
            for (int i = 0; i < 4; i++)
                #pragma unroll
                for (int j = 0; j < 4; j++)
                    acc[i][j] += a[i] * bb[j];
        }
        __syncthreads();
    }
    int cc = c0 + tx * 4;
    float4 blv = *(const float4*)&b_le[cc];
    float bl[4] = {blv.x, blv.y, blv.z, blv.w};
    #pragma unroll
    for (int i = 0; i < 4; i++) {
        int row = row0 + ty * 4 + i;
        int tok = x_tokens[row];
        int b = batch_ids[row], p = pos_ids[row];
        const float* et = &emb_table[tok * HS + cc];
        ushort4 o;
        float v0 = acc[i][0] + bl[0]; v0 = v0 > 0.f ? v0 : 0.f; o.x = f2bf(0.5f * (v0 + et[0]));
        float v1 = acc[i][1] + bl[1]; v1 = v1 > 0.f ? v1 : 0.f; o.y = f2bf(0.5f * (v1 + et[1]));
        float v2 = acc[i][2] + bl[2]; v2 = v2 > 0.f ? v2 : 0.f; o.z = f2bf(0.5f * (v2 + et[2]));
        float v3 = acc[i][3] + bl[3]; v3 = v3 > 0.f ? v3 : 0.f; o.w = f2bf(0.5f * (v3 + et[3]));
        *(ushort4*)&seq[((size_t)b * SPAD + (p + 8)) * HS + cc] = o;
    }
}

// ------- implicit-GEMM conv via bf16 MFMA: [B,SPAD,256]bf16 -> [B,400,128] -
// block: 64 s x 128 oc, 4 waves as 2x2 quadrants (32 s x 64 oc each).
// K = 15 taps x 256 ic, staged BK=64 from pre-packed weights.
__global__ __launch_bounds__(256) void conv_mfma(
    const unsigned short* __restrict__ seq, const unsigned short* __restrict__ Wpk,
    const float* __restrict__ bc, float* __restrict__ convout)
{
    __shared__ unsigned short As[78][264];   // seq rows s0+1 .. s0+78, pad +8
    __shared__ unsigned short Bsh[8192];     // one BK=64 weight stage (16 KB)
    int b  = blockIdx.y;
    int s0 = blockIdx.x * 64;
    int tid = threadIdx.x;
    int w = tid >> 6, lane = tid & 63;
    int q = lane >> 4, m = lane & 15;
    int mh = w >> 1, nh = w & 1;

    // A staging: 78 rows x 256 bf16 = 2496 x 16B slots
    {
        const uint4* sp = (const uint4*)(seq + ((size_t)b * SPAD + s0 + 1) * HS);
        #pragma unroll
        for (int pass = 0; pass < 10; pass++) {
            int idx = pass * 256 + tid;
            if (idx < 2496) {
                int r = idx >> 5, c = idx & 31;
                uint4 v = make_uint4(0u, 0u, 0u, 0u);
                if (s0 + 1 + r < SPAD) v = sp[r * 32 + c];
                *(uint4*)&As[r][c * 8] = v;
            }
        }
    }

    floatx4 acc[2][4] = {};
    const uint4* wp = (const uint4*)Wpk;

    for (int d = 0; d < NTAP; d++) {
        for (int kc = 0; kc < 4; kc++) {
            int stage = d * 4 + kc;
            __syncthreads();   // previous stage's B consumers done (also A visible on 1st)
            #pragma unroll
            for (int c = 0; c < 4; c++) {
                gld_lds16(wp + (size_t)stage * 1024 + c * 256 + tid,
                          &Bsh[(size_t)(c * 256 + w * 64) * 8]);
            }
            __syncthreads();   // drains vmcnt -> B (and A) visible

            #pragma unroll
            for (int ks = 0; ks < 2; ks++) {
                short8 a0 = *(const short8*)&As[mh * 32 + m + d][kc * 64 + ks * 32 + q * 8];
                short8 a1 = *(const short8*)&As[mh * 32 + 16 + m + d][kc * 64 + ks * 32 + q * 8];
                #pragma unroll
                for (int nt = 0; nt < 4; nt++) {
                    short8 bf = *(const short8*)&Bsh[(size_t)((ks * 8 + nh * 4 + nt) * 64 + lane) * 8];
                    acc[0][nt] = __builtin_amdgcn_mfma_f32_16x16x32_bf16(a0, bf, acc[0][nt], 0, 0, 0);
                    acc[1][nt] = __builtin_amdgcn_mfma_f32_16x16x32_bf16(a1, bf, acc[1][nt], 0, 0, 0);
                }
            }
        }
    }

    // C/D layout: col = lane&15, row = (lane>>4)*4 + reg
    #pragma unroll
    for (int nt = 0; nt < 4; nt++) {
        int ocol = nh * 64 + nt * 16 + m;
        float bcv = bc[ocol];
        #pragma unroll
        for (int mt = 0; mt < 2; mt++) {
            #pragma unroll
            for (int r = 0; r < 4; r++) {
                int s = s0 + mh * 32 + mt * 16 + q * 4 + r;
                if (s < LSEQ)
                    convout[((size_t)b * LSEQ + s) * OC + ocol] = acc[mt][nt][r] + bcv;
            }
        }
    }
}

// ------- relu(conv @ Wl1 + bl1), summed over s<400 per batch ---------------
__global__ __launch_bounds__(256) void mlp1_reduce(
    const float* __restrict__ convout, const float* __restrict__ Wl1,
    const float* __restrict__ bl1, float* __restrict__ A_acc)
{
    __shared__ float As[16][68];
    __shared__ float Bs[16][68];
    __shared__ float red[16][64];
    int b  = blockIdx.z;
    int s0 = blockIdx.y * 64;
    int j0 = blockIdx.x * 64;
    int tid = threadIdx.x;
    int tx = tid & 15, ty = tid >> 4;

    int lm  = tid >> 2;
    int lk4 = (tid & 3) * 4;
    int bk  = tid >> 4;
    int bc4 = (tid & 15) * 4;

    float acc[4][4] = {};
    for (int k0 = 0; k0 < OC; k0 += 16) {
        int srow = s0 + lm;
        float4 a4 = make_float4(0.f, 0.f, 0.f, 0.f);
        if (srow < LSEQ)
            a4 = *(const float4*)&convout[((size_t)b * LSEQ + srow) * OC + k0 + lk4];
        As[lk4 + 0][lm] = a4.x; As[lk4 + 1][lm] = a4.y;
        As[lk4 + 2][lm] = a4.z; As[lk4 + 3][lm] = a4.w;
        *(float4*)&Bs[bk][bc4] =
            *(const float4*)&Wl1[(size_t)(k0 + bk) * H1 + j0 + bc4];
        __syncthreads();
        #pragma unroll
        for (int kk = 0; kk < 16; kk++) {
            float4 av = *(const float4*)&As[kk][ty * 4];
            float4 bv = *(const float4*)&Bs[kk][tx * 4];
            float a[4] = {av.x, av.y, av.z, av.w};
            float bb[4] = {bv.x, bv.y, bv.z, bv.w};
            #pragma unroll
            for (int i = 0; i < 4; i++)
                #pragma unroll
                for (int j = 0; j < 4; j++)
                    acc[i][j] += a[i] * bb[j];
        }
        __syncthreads();
    }

    float4 blv = *(const float4*)&bl1[j0 + tx * 4];
    float bl[4] = {blv.x, blv.y, blv.z, blv.w};
    float r[4] = {0.f, 0.f, 0.f, 0.f};
    #pragma unroll
    for (int i = 0; i < 4; i++) {
        int s = s0 + ty * 4 + i;
        if (s < LSEQ) {
            #pragma unroll
            for (int j = 0; j < 4; j++) {
                float v = acc[i][j] + bl[j];
                r[j] += v > 0.f ? v : 0.f;
            }
        }
    }
    #pragma unroll
    for (int j = 0; j < 4; j++) red[ty][tx * 4 + j] = r[j];
    __syncthreads();
    if (tid < 64) {
        float v = 0.f;
        #pragma unroll
        for (int t = 0; t < 16; t++) v += red[t][tid];
        atomicAdd(&A_acc[(size_t)b * H1 + j0 + tid], v);
    }
}

// ------- final: out = A_acc @ Wl2 / 512 + bl2 * (400/512) ------------------
__global__ __launch_bounds__(256) void final_out(
    const float* __restrict__ A_acc, const float* __restrict__ Wl2,
    const float* __restrict__ bl2, float* __restrict__ out)
{
    __shared__ float a[H1];
    int b = blockIdx.x, tid = threadIdx.x;
    a[tid] = A_acc[(size_t)b * H1 + tid];
    a[tid + 256] = A_acc[(size_t)b * H1 + tid + 256];
    __syncthreads();
    float acc = 0.f;
    for (int k = 0; k < H1; k++)
        acc += a[k] * Wl2[(size_t)k * HS + tid];
    out[(size_t)b * HS + tid] = acc * (1.0f / 512.0f) + bl2[tid] * (400.0f / 512.0f);
}

extern "C" void kernel_launch(void* const* d_in, const int* in_sizes, int n_in,
                              void* d_out, int out_size, void* d_ws, size_t ws_size,
                              hipStream_t stream)
{
    const float* emb       = (const float*)d_in[0];
    const int*   x_tokens  = (const int*)d_in[1];
    // d_in[2] edge_src, d_in[3] edge_dst: DEAD (GAT output unused)
    const int*   batch_ids = (const int*)d_in[4];
    const int*   pos_ids   = (const int*)d_in[5];
    // d_in[6] mask: encoded analytically (s < 400, mean over 512)
    const float* emb_table = (const float*)d_in[7];
    // d_in[8..21]: W_e2g/b_e2g + all GAT params: DEAD
    const float* W_le = (const float*)d_in[22];
    const float* b_le = (const float*)d_in[23];
    const float* k7   = (const float*)d_in[24];
    const float* cb7  = (const float*)d_in[25];
    const float* k11  = (const float*)d_in[26];
    const float* cb11 = (const float*)d_in[27];
    const float* k15  = (const float*)d_in[28];
    const float* cb15 = (const float*)d_in[29];
    const float* Wl1  = (const float*)d_in[30];
    const float* bl1  = (const float*)d_in[31];
    const float* Wl2  = (const float*)d_in[32];
    const float* bl2  = (const float*)d_in[33];
    float* out = (float*)d_out;

    // workspace layout (16B-aligned chunks)
    unsigned short* seqb = (unsigned short*)d_ws;                    // [256][416][256] bf16
    float* convout = (float*)((char*)d_ws + (size_t)NBATCH * SPAD * HS * 2);   // [256][400][128]
    unsigned short* Wpk = (unsigned short*)((char*)convout + (size_t)NBATCH * LSEQ * OC * 4); // 15*256*128 bf16
    float* bcv = (float*)((char*)Wpk + (size_t)NTAP * HS * OC * 2);  // [128]
    float* A_acc = (float*)((char*)bcv + 512);                       // [256][512]

    hipMemsetAsync(seqb, 0, (size_t)NBATCH * SPAD * HS * 2, stream);
    hipMemsetAsync(A_acc, 0, (size_t)NBATCH * H1 * sizeof(float), stream);

    combine_pack<<<dim3((NTAP * HS * OC + 255) / 256), 256, 0, stream>>>(
        k7, k11, k15, cb7, cb11, cb15, Wpk, bcv);
    gemm_emb<<<dim3(4, NNODES / 64), 256, 0, stream>>>(
        emb, x_tokens, batch_ids, pos_ids, emb_table, W_le, b_le, seqb);
    conv_mfma<<<dim3(7, NBATCH), 256, 0, stream>>>(seqb, Wpk, bcv, convout);
    mlp1_reduce<<<dim3(8, 7, NBATCH), 256, 0, stream>>>(convout, Wl1, bl1, A_acc);
    final_out<<<NBATCH, 256, 0, stream>>>(A_acc, Wl2, bl2, out);
}

// Round 3
// 730.439 us; speedup vs baseline: 3.4770x; 1.6431x over previous
//
#include <hip/hip_runtime.h>

#define NNODES 102400
#define NBATCH 256
#define LSEQ   400
#define SPAD   416   // 8 zero pad rows each side of the 400 valid positions
#define HS     256
#define KDIM   640
#define OC     128
#define NTAP   15
#define H1     512

typedef __attribute__((ext_vector_type(8))) short short8;
typedef __attribute__((ext_vector_type(4))) float floatx4;

__device__ inline unsigned short f2bf(float f) {
    unsigned u = __builtin_bit_cast(unsigned, f);
    unsigned r = (u + 0x7FFFu + ((u >> 16) & 1u)) >> 16;
    return (unsigned short)r;
}

__device__ inline void gld_lds16(const void* g, void* l) {
    __builtin_amdgcn_global_load_lds(
        (const __attribute__((address_space(1))) unsigned int*)g,
        (__attribute__((address_space(3))) unsigned int*)l, 16, 0, 0);
}

// ------- combine k7/k11/k15 (+/3) into one 15-tap weight, packed in MFMA
// ------- B-fragment order, bf16 (stage = (d,kc): BK=64 ic, all 128 oc).
__global__ __launch_bounds__(256) void combine_pack(
    const float* __restrict__ k7, const float* __restrict__ k11,
    const float* __restrict__ k15, const float* __restrict__ cb7,
    const float* __restrict__ cb11, const float* __restrict__ cb15,
    unsigned short* __restrict__ Wpk, float* __restrict__ bc)
{
    int idx = blockIdx.x * 256 + threadIdx.x;
    if (idx < NTAP * HS * OC) {
        int oc = idx & (OC - 1);
        int ic = (idx >> 7) & (HS - 1);
        int d  = idx / (OC * HS);
        float w = k15[(oc * HS + ic) * 15 + d];
        int t11 = d - 2;
        if (t11 >= 0 && t11 < 11) w += k11[(oc * HS + ic) * 11 + t11];
        int t7 = d - 4;
        if (t7 >= 0 && t7 < 7)   w += k7[(oc * HS + ic) * 7 + t7];
        w *= (1.0f / 3.0f);
        int kc = ic >> 6, ks = (ic >> 5) & 1, q = (ic >> 3) & 3, j = ic & 7;
        int nt = oc >> 4, n = oc & 15;
        int pidx = ((((d * 4 + kc) * 2 + ks) * 8 + nt) * 64 + (q * 16 + n)) * 8 + j;
        Wpk[pidx] = f2bf(w);
    }
    if (idx < OC) bc[idx] = (cb7[idx] + cb11[idx] + cb15[idx]) * (1.0f / 3.0f);
}

// ------- pack W_le [640][256] -> bf16 fragment order (10 stages of BK=64) --
__global__ __launch_bounds__(256) void pack_Wle(
    const float* __restrict__ W, unsigned short* __restrict__ P)
{
    int idx = blockIdx.x * 256 + threadIdx.x;   // 640*256
    int k = idx >> 8, col = idx & 255;
    int t = k >> 6, ks = (k >> 5) & 1, q = (k >> 3) & 3, j = k & 7;
    int nt = col >> 4, n = col & 15;
    int pidx = (((t * 2 + ks) * 16 + nt) * 64 + (q * 16 + n)) * 8 + j;
    P[pidx] = f2bf(W[k * 256 + col]);
}

// ------- pack Wl1 [128][512] -> bf16 fragment order (4 j-blocks of 128) ----
__global__ __launch_bounds__(256) void pack_Wl1(
    const float* __restrict__ W, unsigned short* __restrict__ P)
{
    int idx = blockIdx.x * 256 + threadIdx.x;   // 128*512
    int k = idx >> 9, col = idx & 511;
    int ks = k >> 5, q = (k >> 3) & 3, j = k & 7;
    int jb = col >> 7, nhnt = (col >> 4) & 7, n = col & 15;
    int pidx = jb * 16384 + ((ks * 8 + nhnt) * 64 + (q * 16 + n)) * 8 + j;
    P[pidx] = f2bf(W[k * 512 + col]);
}

// ------- MFMA: relu(emb @ W_le + b_le), + (x_r + .)/2 scatter into bf16 seq
// block: 64 rows x 256 cols; waves 2x2 (32 rows x 128 cols each); K=640.
__global__ __launch_bounds__(256) void gemm_emb(
    const float* __restrict__ emb, const int* __restrict__ x_tokens,
    const int* __restrict__ batch_ids, const int* __restrict__ pos_ids,
    const float* __restrict__ emb_table,
    const unsigned short* __restrict__ Wle_pk, const float* __restrict__ b_le,
    unsigned short* __restrict__ seq)
{
    __shared__ unsigned short As[64][72];   // stride 72 shorts = 36 dw === 4 mod 32
    __shared__ unsigned short Bsh[16384];   // one BK=64 stage, all 256 cols (32 KB)
    int row0 = blockIdx.x * 64;
    int tid = threadIdx.x;
    int w = tid >> 6, lane = tid & 63;
    int q = lane >> 4, m = lane & 15;
    int mh = w >> 1, nh = w & 1;

    int ar = tid >> 2;            // A-stage row 0..63
    int ac = (tid & 3) * 16;      // A-stage col (floats) 0,16,32,48

    floatx4 acc[2][8] = {};
    const uint4* wp = (const uint4*)Wle_pk;

    for (int t = 0; t < 10; t++) {
        __syncthreads();
        // A: 64 rows x 64 k fp32 -> bf16 LDS
        {
            const float4* src = (const float4*)&emb[(size_t)(row0 + ar) * KDIM + t * 64 + ac];
            #pragma unroll
            for (int u = 0; u < 4; u++) {
                float4 f = src[u];
                ushort4 h;
                h.x = f2bf(f.x); h.y = f2bf(f.y); h.z = f2bf(f.z); h.w = f2bf(f.w);
                *(ushort4*)&As[ar][ac + u * 4] = h;
            }
        }
        // B: 32 KB pre-packed stage via global_load_lds
        #pragma unroll
        for (int i = 0; i < 8; i++) {
            gld_lds16(wp + (size_t)t * 2048 + i * 256 + tid,
                      &Bsh[(size_t)(i * 256 + w * 64) * 8]);
        }
        __syncthreads();

        #pragma unroll
        for (int ks = 0; ks < 2; ks++) {
            short8 a0 = *(const short8*)&As[mh * 32 + m][ks * 32 + q * 8];
            short8 a1 = *(const short8*)&As[mh * 32 + 16 + m][ks * 32 + q * 8];
            #pragma unroll
            for (int nt = 0; nt < 8; nt++) {
                short8 bf = *(const short8*)&Bsh[(size_t)((ks * 16 + nh * 8 + nt) * 64 + lane) * 8];
                acc[0][nt] = __builtin_amdgcn_mfma_f32_16x16x32_bf16(a0, bf, acc[0][nt], 0, 0, 0);
                acc[1][nt] = __builtin_amdgcn_mfma_f32_16x16x32_bf16(a1, bf, acc[1][nt], 0, 0, 0);
            }
        }
    }

    // C/D: col = lane&15 (within 16-tile), row = q*4 + reg
    #pragma unroll
    for (int nt = 0; nt < 8; nt++) {
        int col = nh * 128 + nt * 16 + m;
        float blv = b_le[col];
        #pragma unroll
        for (int mt = 0; mt < 2; mt++) {
            #pragma unroll
            for (int r = 0; r < 4; r++) {
                int row = row0 + mh * 32 + mt * 16 + q * 4 + r;
                int tok = x_tokens[row];
                int b = batch_ids[row], p = pos_ids[row];
                float v = acc[mt][nt][r] + blv;
                v = v > 0.f ? v : 0.f;
                seq[((size_t)b * SPAD + (p + 8)) * HS + col] =
                    f2bf(0.5f * (v + emb_table[tok * HS + col]));
            }
        }
    }
}

// ------- implicit-GEMM conv via bf16 MFMA: [B,SPAD,256]bf16 -> [B,400,128]bf16
__global__ __launch_bounds__(256) void conv_mfma(
    const unsigned short* __restrict__ seq, const unsigned short* __restrict__ Wpk,
    const float* __restrict__ bc, unsigned short* __restrict__ convout)
{
    __shared__ unsigned short As[78][264];
    __shared__ unsigned short Bsh[8192];
    int b  = blockIdx.y;
    int s0 = blockIdx.x * 64;
    int tid = threadIdx.x;
    int w = tid >> 6, lane = tid & 63;
    int q = lane >> 4, m = lane & 15;
    int mh = w >> 1, nh = w & 1;

    {
        const uint4* sp = (const uint4*)(seq + ((size_t)b * SPAD + s0 + 1) * HS);
        #pragma unroll
        for (int pass = 0; pass < 10; pass++) {
            int idx = pass * 256 + tid;
            if (idx < 2496) {
                int r = idx >> 5, c = idx & 31;
                uint4 v = make_uint4(0u, 0u, 0u, 0u);
                if (s0 + 1 + r < SPAD) v = sp[r * 32 + c];
                *(uint4*)&As[r][c * 8] = v;
            }
        }
    }

    floatx4 acc[2][4] = {};
    const uint4* wp = (const uint4*)Wpk;

    for (int d = 0; d < NTAP; d++) {
        for (int kc = 0; kc < 4; kc++) {
            int stage = d * 4 + kc;
            __syncthreads();
            #pragma unroll
            for (int c = 0; c < 4; c++) {
                gld_lds16(wp + (size_t)stage * 1024 + c * 256 + tid,
                          &Bsh[(size_t)(c * 256 + w * 64) * 8]);
            }
            __syncthreads();

            #pragma unroll
            for (int ks = 0; ks < 2; ks++) {
                short8 a0 = *(const short8*)&As[mh * 32 + m + d][kc * 64 + ks * 32 + q * 8];
                short8 a1 = *(const short8*)&As[mh * 32 + 16 + m + d][kc * 64 + ks * 32 + q * 8];
                #pragma unroll
                for (int nt = 0; nt < 4; nt++) {
                    short8 bf = *(const short8*)&Bsh[(size_t)((ks * 8 + nh * 4 + nt) * 64 + lane) * 8];
                    acc[0][nt] = __builtin_amdgcn_mfma_f32_16x16x32_bf16(a0, bf, acc[0][nt], 0, 0, 0);
                    acc[1][nt] = __builtin_amdgcn_mfma_f32_16x16x32_bf16(a1, bf, acc[1][nt], 0, 0, 0);
                }
            }
        }
    }

    #pragma unroll
    for (int nt = 0; nt < 4; nt++) {
        int ocol = nh * 64 + nt * 16 + m;
        float bcv = bc[ocol];
        #pragma unroll
        for (int mt = 0; mt < 2; mt++) {
            #pragma unroll
            for (int r = 0; r < 4; r++) {
                int s = s0 + mh * 32 + mt * 16 + q * 4 + r;
                if (s < LSEQ)
                    convout[((size_t)b * LSEQ + s) * OC + ocol] = f2bf(acc[mt][nt][r] + bcv);
            }
        }
    }
}

// ------- MFMA: colsum_{s<400} relu(convout @ Wl1 + bl1) -> A_acc -----------
// block: 64 s x 128 j; K=128 in one stage; waves 2x2 (32s x 64j).
__global__ __launch_bounds__(256) void mlp1_mfma(
    const unsigned short* __restrict__ convout, const unsigned short* __restrict__ Wl1_pk,
    const float* __restrict__ bl1, float* __restrict__ A_acc)
{
    __shared__ unsigned short As[64][136];  // 136 shorts = 68 dw === 4 mod 32
    __shared__ unsigned short Bsh[16384];   // 128x128 bf16 (32 KB)
    int b  = blockIdx.z;
    int s0 = blockIdx.y * 64;
    int jb = blockIdx.x;
    int tid = threadIdx.x;
    int w = tid >> 6, lane = tid & 63;
    int q = lane >> 4, m = lane & 15;
    int mh = w >> 1, nh = w & 1;

    // A: rows s0..s0+63 of convout[b] (bf16, guard >=400 -> 0)
    {
        int r = tid >> 2;
        int c = (tid & 3) * 32;   // shorts
        const uint4* src = (const uint4*)&convout[((size_t)b * LSEQ + s0 + r) * OC + c];
        bool ok = (s0 + r) < LSEQ;
        #pragma unroll
        for (int u = 0; u < 4; u++) {
            uint4 v = make_uint4(0u, 0u, 0u, 0u);
            if (ok) v = src[u];
            *(uint4*)&As[r][c + u * 8] = v;
        }
    }
    // B: pre-packed j-block stage
    {
        const uint4* wp = (const uint4*)(Wl1_pk + (size_t)jb * 16384);
        #pragma unroll
        for (int i = 0; i < 8; i++) {
            gld_lds16(wp + i * 256 + tid, &Bsh[(size_t)(i * 256 + w * 64) * 8]);
        }
    }
    __syncthreads();

    floatx4 acc[2][4] = {};
    #pragma unroll
    for (int ks = 0; ks < 4; ks++) {
        short8 a0 = *(const short8*)&As[mh * 32 + m][ks * 32 + q * 8];
        short8 a1 = *(const short8*)&As[mh * 32 + 16 + m][ks * 32 + q * 8];
        #pragma unroll
        for (int nt = 0; nt < 4; nt++) {
            short8 bf = *(const short8*)&Bsh[(size_t)((ks * 8 + nh * 4 + nt) * 64 + lane) * 8];
            acc[0][nt] = __builtin_amdgcn_mfma_f32_16x16x32_bf16(a0, bf, acc[0][nt], 0, 0, 0);
            acc[1][nt] = __builtin_amdgcn_mfma_f32_16x16x32_bf16(a1, bf, acc[1][nt], 0, 0, 0);
        }
    }

    // epilogue: j = jb*128 + nh*64 + nt*16 + m ; s = s0 + mh*32 + mt*16 + q*4 + r
    #pragma unroll
    for (int nt = 0; nt < 4; nt++) {
        int j = jb * 128 + nh * 64 + nt * 16 + m;
        float blv = bl1[j];
        float vsum = 0.f;
        #pragma unroll
        for (int mt = 0; mt < 2; mt++) {
            int sbase = s0 + mh * 32 + mt * 16 + q * 4;
            #pragma unroll
            for (int r = 0; r < 4; r++) {
                if (sbase + r < LSEQ) {
                    float v = acc[mt][nt][r] + blv;
                    vsum += v > 0.f ? v : 0.f;
                }
            }
        }
        vsum += __shfl_xor(vsum, 16, 64);
        vsum += __shfl_xor(vsum, 32, 64);
        if (q == 0) atomicAdd(&A_acc[(size_t)b * H1 + j], vsum);
    }
}

// ------- final: out = A_acc @ Wl2 / 512 + bl2 * (400/512), 4 batches/block -
__global__ __launch_bounds__(256) void final_out(
    const float* __restrict__ A_acc, const float* __restrict__ Wl2,
    const float* __restrict__ bl2, float* __restrict__ out)
{
    __shared__ float a[4][H1];
    int b0 = blockIdx.x * 4, tid = threadIdx.x;
    #pragma unroll
    for (int i = 0; i < 8; i++) {
        int flat = i * 256 + tid;
        a[flat >> 9][flat & 511] = A_acc[(size_t)b0 * H1 + flat];
    }
    __syncthreads();
    float acc[4] = {};
    for (int k = 0; k < H1; k++) {
        float wv = Wl2[(size_t)k * HS + tid];
        #pragma unroll
        for (int i = 0; i < 4; i++) acc[i] += a[i][k] * wv;
    }
    float bb = bl2[tid] * (400.0f / 512.0f);
    #pragma unroll
    for (int i = 0; i < 4; i++)
        out[(size_t)(b0 + i) * HS + tid] = acc[i] * (1.0f / 512.0f) + bb;
}

extern "C" void kernel_launch(void* const* d_in, const int* in_sizes, int n_in,
                              void* d_out, int out_size, void* d_ws, size_t ws_size,
                              hipStream_t stream)
{
    const float* emb       = (const float*)d_in[0];
    const int*   x_tokens  = (const int*)d_in[1];
    // d_in[2] edge_src, d_in[3] edge_dst: DEAD (GAT output unused)
    const int*   batch_ids = (const int*)d_in[4];
    const int*   pos_ids   = (const int*)d_in[5];
    // d_in[6] mask: encoded analytically (s < 400, mean over 512)
    const float* emb_table = (const float*)d_in[7];
    // d_in[8..21]: W_e2g/b_e2g + all GAT params: DEAD
    const float* W_le = (const float*)d_in[22];
    const float* b_le = (const float*)d_in[23];
    const float* k7   = (const float*)d_in[24];
    const float* cb7  = (const float*)d_in[25];
    const float* k11  = (const float*)d_in[26];
    const float* cb11 = (const float*)d_in[27];
    const float* k15  = (const float*)d_in[28];
    const float* cb15 = (const float*)d_in[29];
    const float* Wl1  = (const float*)d_in[30];
    const float* bl1  = (const float*)d_in[31];
    const float* Wl2  = (const float*)d_in[32];
    const float* bl2  = (const float*)d_in[33];
    float* out = (float*)d_out;

    // workspace layout (16B-aligned chunks)
    char* p = (char*)d_ws;
    unsigned short* seqb = (unsigned short*)p;       p += (size_t)NBATCH * SPAD * HS * 2;
    unsigned short* convout = (unsigned short*)p;    p += (size_t)NBATCH * LSEQ * OC * 2;
    unsigned short* Wpk = (unsigned short*)p;        p += (size_t)NTAP * HS * OC * 2;
    unsigned short* Wle_pk = (unsigned short*)p;     p += (size_t)KDIM * HS * 2;
    unsigned short* Wl1_pk = (unsigned short*)p;     p += (size_t)OC * H1 * 2;
    float* bcv = (float*)p;                          p += 512;
    float* A_acc = (float*)p;                        p += (size_t)NBATCH * H1 * 4;

    hipMemsetAsync(seqb, 0, (size_t)NBATCH * SPAD * HS * 2, stream);
    hipMemsetAsync(A_acc, 0, (size_t)NBATCH * H1 * sizeof(float), stream);

    combine_pack<<<dim3((NTAP * HS * OC + 255) / 256), 256, 0, stream>>>(
        k7, k11, k15, cb7, cb11, cb15, Wpk, bcv);
    pack_Wle<<<dim3(KDIM * HS / 256), 256, 0, stream>>>(W_le, Wle_pk);
    pack_Wl1<<<dim3(OC * H1 / 256), 256, 0, stream>>>(Wl1, Wl1_pk);
    gemm_emb<<<dim3(NNODES / 64), 256, 0, stream>>>(
        emb, x_tokens, batch_ids, pos_ids, emb_table, Wle_pk, b_le, seqb);
    conv_mfma<<<dim3(7, NBATCH), 256, 0, stream>>>(seqb, Wpk, bcv, convout);
    mlp1_mfma<<<dim3(4, 7, NBATCH), 256, 0, stream>>>(convout, Wl1_pk, bl1, A_acc);
    final_out<<<NBATCH / 4, 256, 0, stream>>>(A_acc, Wl2, bl2, out);
}